// Round 5
// baseline (261.356 us; speedup 1.0000x reference)
//
#include <hip/hip_runtime.h>

#define C 256
#define HW 4096
#define STRIDE 66     // dwords per act row in LDS (64 px + 2 pad) -> verified 2-way-free read banks
#define NCHUNK 8

typedef __attribute__((ext_vector_type(8))) short short8;
typedef __attribute__((ext_vector_type(4))) float float4v;

__device__ __forceinline__ unsigned short f2bf(float x) {
    unsigned u = __builtin_bit_cast(unsigned, x);
    u = (u + 0x7fffu + ((u >> 16) & 1u)) >> 16;
    return (unsigned short)u;
}

// async global->LDS DMA: 64 lanes x 16B (A-table only)
__device__ __forceinline__ void g2l_b128(const void* g, void* l) {
    __builtin_amdgcn_global_load_lds(
        (const __attribute__((address_space(1))) unsigned int*)g,
        (__attribute__((address_space(3))) unsigned int*)l, 16, 0, 0);
}

// Kernel 1: one block. g = IDFT(1/(1 - DFT(kernel))), then expanded A-fragment table:
// tab[(s*64 + lane)*8 + j] = bf16(gsh[(m - 16s - 8q - j) & 255]), m=lane&15, q=lane>>4.
// (Byte-identical to the verified round-0/4 kernel.)
__global__ void build_tab_kernel(const float* __restrict__ filt, unsigned short* __restrict__ tab) {
    __shared__ float twc[256], tws[256];
    __shared__ float Gre[256], Gim[256];
    __shared__ float gsh[256];
    const int t = threadIdx.x;
    const double PI = 3.14159265358979323846;
    double th = (double)t * (PI / 128.0);      // 2*pi*t/256
    twc[t] = (float)cos(th);
    tws[t] = (float)sin(th);
    __syncthreads();
    float re = 1.0f, im = 0.0f;
    for (int i = 0; i < 27; ++i) {
        int d = (243 + i) & 255;               // pad_roll layout offsets
        int idx = (t * d) & 255;
        float fv = filt[i];
        re -= fv * twc[idx];
        im += fv * tws[idx];
    }
    float den = re * re + im * im;
    Gre[t] = re / den;
    Gim[t] = -im / den;
    __syncthreads();
    float acc = 0.0f;
    for (int f = 0; f < 256; ++f) {
        int idx = (f * t) & 255;
        acc += Gre[f] * twc[idx] - Gim[f] * tws[idx];
    }
    gsh[t] = acc * (1.0f / 256.0f);
    __syncthreads();
    for (int e = t; e < 16 * 64 * 8; e += 256) {
        int j = e & 7;
        int lane = (e >> 3) & 63;
        int s = e >> 9;
        int mm = lane & 15, q = lane >> 4;
        int src = (mm - 16 * s - 8 * q - j) & 255;
        tab[e] = f2bf(gsh[src]);
    }
}

// Kernel 2: out[c,p] = sum_k W[c,k]*act[k,p].
// Block: 256 c x 64 px tile. Reg-staged K-pipeline (T14): each wave loads its 8 rows of
// chunk c+3 into registers (2x dwordx4 = 1-KB/instr), ds_writes chunk c+1 into a 2-buffer
// LDS one phase before consumption. In-flight bytes live in VGPRs (3 chunks deep) instead
// of LDS buffers -> LDS 33 KB -> 4 blocks/CU (16 waves). All VMEM waits are compiler-
// managed register deps; barriers are raw s_barrier + lgkmcnt(0) (never a vmcnt(0) drain).
__global__ __launch_bounds__(256, 4)
void toeplitz_gemm_kernel(const float* __restrict__ act,
                          const unsigned short* __restrict__ tab,
                          float* __restrict__ out) {
    __shared__ float chunkbuf[2][32 * STRIDE];            // 2 x 8448 B = 16896 B
    __shared__ unsigned short afrags[16 * 64 * 8];        // 16384 B  (total 33280 -> 4 blocks/CU)

    const int tid = threadIdx.x;
    const int wave = tid >> 6;
    const int lane = tid & 63;
    const int m = lane & 15;        // MFMA row (A) / col (B,D)
    const int quad = lane >> 4;     // k-subchunk selector / staging row-sub
    const int pxd = (lane & 15) << 2;   // staging dword-px 0,4,...,60
    const int blk = blockIdx.x;
    const int n = blk >> 6;                 // 64 px-tiles per image
    const int p0 = (blk & 63) << 6;
    const float* __restrict__ actn = act + (size_t)n * (C * HW);
    float* __restrict__ outn = out + (size_t)n * (C * HW);

    // ---- A-fragment table: 16 KB global -> LDS, 16B/lane DMA (4 ops/wave, issued FIRST) ----
#pragma unroll
    for (int i = 0; i < 4; ++i) {
        const int seg = wave * 4 + i;                      // 16 segments of 1024 B
        g2l_b128(tab + seg * 512 + lane * 8, &afrags[seg * 512]);
    }
    asm volatile("" ::: "memory");   // pin: DMA issues precede staging loads (in-order vmcnt)

    // per-lane staging source: rows wave*8 + quad (+4), px dwords pxd..pxd+3
    const float* __restrict__ srcp = actn + (size_t)(wave * 8) * HW + p0 + pxd;

    uint4 sA[3], sB[3];   // 3-deep chunk slots (all indices compile-time -> registers)

    // load chunk c into slot c%3 (2 x global_load_dwordx4 = 2 x 1 KB per wave)
#define RL(c)                                                                     \
    {                                                                             \
        sA[(c) % 3] = *(const uint4*)(srcp + (size_t)((c) * 32 + quad) * HW);     \
        sB[(c) % 3] = *(const uint4*)(srcp + (size_t)((c) * 32 + 4 + quad) * HW); \
    }
    // write chunk c from slot c%3 into LDS buffer c&1 (4 x ds_write_b64; rows are 8B-aligned)
#define WR(c)                                                                     \
    {                                                                             \
        float* dst = &chunkbuf[(c) & 1][(wave * 8 + quad) * STRIDE + pxd];        \
        uint2 t0, t1, t2, t3;                                                     \
        t0.x = sA[(c) % 3].x; t0.y = sA[(c) % 3].y;                               \
        t1.x = sA[(c) % 3].z; t1.y = sA[(c) % 3].w;                               \
        t2.x = sB[(c) % 3].x; t2.y = sB[(c) % 3].y;                               \
        t3.x = sB[(c) % 3].z; t3.y = sB[(c) % 3].w;                               \
        *(uint2*)(dst) = t0;                                                      \
        *(uint2*)(dst + 2) = t1;                                                  \
        *(uint2*)(dst + 4 * STRIDE) = t2;                                         \
        *(uint2*)(dst + 4 * STRIDE + 2) = t3;                                     \
    }
    // raw barrier: drain own LDS ops, never vmcnt
#define BARRIER()                                                                 \
    {                                                                             \
        asm volatile("s_waitcnt lgkmcnt(0)" ::: "memory");                        \
        __builtin_amdgcn_s_barrier();                                             \
        asm volatile("" ::: "memory");                                            \
    }

    // ---- prologue: 3 chunks in flight + afrags; wait only afrags (keep chunks flying) ----
    RL(0) RL(1) RL(2)
    asm volatile("s_waitcnt vmcnt(6)" ::: "memory");   // retires the 4 afrag DMAs exactly
    __builtin_amdgcn_sched_barrier(0);
    WR(0)            // compiler inserts vmcnt wait for chunk-0 regs only
    BARRIER()        // afrags + chunk 0 visible to all waves

    float4v acc[4][4];
#pragma unroll
    for (int ct = 0; ct < 4; ++ct)
#pragma unroll
        for (int pt = 0; pt < 4; ++pt)
            acc[ct][pt] = (float4v){0.f, 0.f, 0.f, 0.f};

    // compute chunk c from LDS buffer c&1 (verified 66-stride read banks + pack + MFMA)
#define COMPUTE(c)                                                                \
    {                                                                             \
        const float* cb = &chunkbuf[(c) & 1][0];                                  \
        short8 bfr[4];                                                            \
        _Pragma("unroll")                                                         \
        for (int pt = 0; pt < 4; ++pt) {                                          \
            const float* base = cb + (quad * 8) * STRIDE + pt * 16 + m;           \
            unsigned u[8];                                                        \
            _Pragma("unroll")                                                     \
            for (int j = 0; j < 8; ++j)                                           \
                u[j] = __builtin_bit_cast(unsigned, base[j * STRIDE]) + 0x8000u;  \
            uint4 pk;                                                             \
            pk.x = (u[0] >> 16) | (u[1] & 0xFFFF0000u);                           \
            pk.y = (u[2] >> 16) | (u[3] & 0xFFFF0000u);                           \
            pk.z = (u[4] >> 16) | (u[5] & 0xFFFF0000u);                           \
            pk.w = (u[6] >> 16) | (u[7] & 0xFFFF0000u);                           \
            bfr[pt] = __builtin_bit_cast(short8, pk);                             \
        }                                                                         \
        _Pragma("unroll")                                                         \
        for (int ct = 0; ct < 4; ++ct) {                                          \
            const int sp = (2 * (c) - ct - 4 * wave) & 15;                        \
            const short8 af = *(const short8*)&afrags[sp * 512 + lane * 8];       \
            _Pragma("unroll")                                                     \
            for (int pt = 0; pt < 4; ++pt)                                        \
                acc[ct][pt] = __builtin_amdgcn_mfma_f32_16x16x32_bf16(            \
                    af, bfr[pt], acc[ct][pt], 0, 0, 0);                           \
        }                                                                         \
    }

    // Phase c: issue chunk c+3 loads (slot c%3 was freed by WR(c) last phase);
    // ds_write chunk c+1 into buffer (c+1)&1 (its readers finished before the last
    // barrier); compute chunk c; barrier publishes chunk c+1.
#define PHASE(c)                                                                  \
    {                                                                             \
        if ((c) + 3 < NCHUNK) RL((c) + 3)                                         \
        if ((c) + 1 < NCHUNK) WR((c) + 1)                                         \
        COMPUTE(c)                                                                \
        if ((c) < NCHUNK - 1) BARRIER()                                           \
    }

    PHASE(0) PHASE(1) PHASE(2) PHASE(3)
    PHASE(4) PHASE(5) PHASE(6) PHASE(7)
#undef PHASE
#undef COMPUTE
#undef BARRIER
#undef WR
#undef RL

    // ---- epilogue (verified rounds 0-4): D layout col=lane&15, row=quad*4+r ----
#pragma unroll
    for (int ct = 0; ct < 4; ++ct) {
#pragma unroll
        for (int r = 0; r < 4; ++r) {
            const int cc = wave * 64 + ct * 16 + quad * 4 + r;
            float* op = outn + (size_t)cc * HW + p0;
#pragma unroll
            for (int pt = 0; pt < 4; ++pt) {
                op[pt * 16 + m] = acc[ct][pt][r];
            }
        }
    }
}

extern "C" void kernel_launch(void* const* d_in, const int* in_sizes, int n_in,
                              void* d_out, int out_size, void* d_ws, size_t ws_size,
                              hipStream_t stream) {
    const float* act = (const float*)d_in[0];
    const float* filt = (const float*)d_in[1];
    float* out = (float*)d_out;
    unsigned short* tab = (unsigned short*)d_ws;   // 16384 bytes used

    build_tab_kernel<<<1, 256, 0, stream>>>(filt, tab);
    toeplitz_gemm_kernel<<<2048, 256, 0, stream>>>(act, tab, out);
}

// Round 6
// 254.269 us; speedup vs baseline: 1.0279x; 1.0279x over previous
//
#include <hip/hip_runtime.h>

#define C 256
#define HW 4096
#define STRIDE 66     // dwords per act row in LDS (64 px + 2 pad) -> verified 0-conflict read banks
#define CHROWS 32     // rows per K-chunk
#define NCHUNK 8
#define NBUF 4

typedef __attribute__((ext_vector_type(8))) short short8;
typedef __attribute__((ext_vector_type(4))) float float4v;

__device__ __forceinline__ unsigned short f2bf(float x) {
    unsigned u = __builtin_bit_cast(unsigned, x);
    u = (u + 0x7fffu + ((u >> 16) & 1u)) >> 16;
    return (unsigned short)u;
}

// async global->LDS DMA: 64 lanes x 4B, LDS dst = wave-uniform base + lane*4 (256 B/instr, full lines)
__device__ __forceinline__ void g2l_b32(const void* g, void* l) {
    __builtin_amdgcn_global_load_lds(
        (const __attribute__((address_space(1))) unsigned int*)g,
        (__attribute__((address_space(3))) unsigned int*)l, 4, 0, 0);
}
// async global->LDS DMA: 64 lanes x 16B
__device__ __forceinline__ void g2l_b128(const void* g, void* l) {
    __builtin_amdgcn_global_load_lds(
        (const __attribute__((address_space(1))) unsigned int*)g,
        (__attribute__((address_space(3))) unsigned int*)l, 16, 0, 0);
}

template <int N>
__device__ __forceinline__ void wait_vmcnt() {
    asm volatile("s_waitcnt vmcnt(%0)" :: "n"(N) : "memory");
    __builtin_amdgcn_sched_barrier(0);   // rule #18: pin -- nothing crosses the counted wait
}

// Kernel 1: one block. g = IDFT(1/(1 - DFT(kernel))), then expanded A-fragment table:
// tab[(s*64 + lane)*8 + j] = bf16(gsh[(m - 16s - 8q - j) & 255]), m=lane&15, q=lane>>4.
// (Byte-identical to the verified round-0/4 kernel.)
__global__ void build_tab_kernel(const float* __restrict__ filt, unsigned short* __restrict__ tab) {
    __shared__ float twc[256], tws[256];
    __shared__ float Gre[256], Gim[256];
    __shared__ float gsh[256];
    const int t = threadIdx.x;
    const double PI = 3.14159265358979323846;
    double th = (double)t * (PI / 128.0);      // 2*pi*t/256
    twc[t] = (float)cos(th);
    tws[t] = (float)sin(th);
    __syncthreads();
    float re = 1.0f, im = 0.0f;
    for (int i = 0; i < 27; ++i) {
        int d = (243 + i) & 255;               // pad_roll layout offsets
        int idx = (t * d) & 255;
        float fv = filt[i];
        re -= fv * twc[idx];
        im += fv * tws[idx];
    }
    float den = re * re + im * im;
    Gre[t] = re / den;
    Gim[t] = -im / den;
    __syncthreads();
    float acc = 0.0f;
    for (int f = 0; f < 256; ++f) {
        int idx = (f * t) & 255;
        acc += Gre[f] * twc[idx] - Gim[f] * tws[idx];
    }
    gsh[t] = acc * (1.0f / 256.0f);
    __syncthreads();
    for (int e = t; e < 16 * 64 * 8; e += 256) {
        int j = e & 7;
        int lane = (e >> 3) & 63;
        int s = e >> 9;
        int mm = lane & 15, q = lane >> 4;
        int src = (mm - 16 * s - 8 * q - j) & 255;
        tab[e] = f2bf(gsh[src]);
    }
}

// Kernel 2: out[c,p] = sum_k W[c,k]*act[k,p].
// Round-4 structure (verified 87 us): 256 c x 64 px tile, full-line 256-B DMA reads,
// K pipelined in 8 chunks of 32 rows, 4 LDS buffers, counted s_waitcnt vmcnt(N) + raw
// s_barrier (prefetches never drained in the main loop).
// Round-6 delta: NON-TEMPORAL epilogue stores. act(128MB)+out(128MB) exactly fill the
// 256-MB LLC; default-policy out lines were evicting half of act each iteration
// (FETCH=66MB of a 128MB input). nt stores mark out lines evict-first -> act stays
// LLC-resident -> act read misses become LLC hits -> effective latency ~halves.
__global__ __launch_bounds__(256, 3)
void toeplitz_gemm_kernel(const float* __restrict__ act,
                          const unsigned short* __restrict__ tab,
                          float* __restrict__ out) {
    __shared__ float chunkbuf[NBUF][CHROWS * STRIDE];     // 4 x 8448 B = 33792 B
    __shared__ unsigned short afrags[16 * 64 * 8];        // 16384 B  (total 50176 -> 3 blocks/CU)

    const int tid = threadIdx.x;
    const int wave = tid >> 6;
    const int lane = tid & 63;
    const int m = lane & 15;        // MFMA row (A) / col (B,D)
    const int quad = lane >> 4;     // k-subchunk selector
    const int blk = blockIdx.x;
    const int n = blk >> 6;                 // 64 px-tiles per image
    const int p0 = (blk & 63) << 6;
    const float* __restrict__ actn = act + (size_t)n * (C * HW);
    float* __restrict__ outn = out + (size_t)n * (C * HW);

    // ---- A-fragment table: 16 KB global -> LDS, 16B/lane DMA (4 ops/wave) ----
#pragma unroll
    for (int i = 0; i < 4; ++i) {
        const int seg = wave * 4 + i;                      // 16 segments of 1024 B
        g2l_b128(tab + seg * 512 + lane * 8, &afrags[seg * 512]);
    }

    // issue one 32-row chunk (8 full-line DMAs per wave)
    auto issue = [&](int ch) {
        const float* src = actn + (size_t)(ch * CHROWS + wave * 8) * HW + p0 + lane;
#pragma unroll
        for (int i = 0; i < 8; ++i)
            g2l_b32(src + (size_t)i * HW, &chunkbuf[ch & (NBUF - 1)][(wave * 8 + i) * STRIDE]);
    };

    issue(0); issue(1); issue(2);            // prologue: depth-3 in flight (+afrags)

    float4v acc[4][4];
#pragma unroll
    for (int ct = 0; ct < 4; ++ct)
#pragma unroll
        for (int pt = 0; pt < 4; ++pt)
            acc[ct][pt] = (float4v){0.f, 0.f, 0.f, 0.f};

    // Phase c: wait own chunk-c DMAs retired (<=16 outstanding keeps c+1,c+2 flying),
    // barrier makes all waves' chunk-c rows visible, then issue c+3 (its buffer was
    // last read in phase c-1, so the phase-c barrier proves it is free), then compute.
#define PHASE(c, WN)                                                              \
    {                                                                             \
        wait_vmcnt<WN>();                                                         \
        __builtin_amdgcn_s_barrier();                                             \
        __builtin_amdgcn_sched_barrier(0);                                        \
        asm volatile("" ::: "memory");                                            \
        if ((c) + 3 < NCHUNK) issue((c) + 3);                                     \
        const float* cb = &chunkbuf[(c) & (NBUF - 1)][0];                         \
        short8 bfr[4];                                                            \
        _Pragma("unroll")                                                         \
        for (int pt = 0; pt < 4; ++pt) {                                          \
            const float* base = cb + (quad * 8) * STRIDE + pt * 16 + m;           \
            unsigned u[8];                                                        \
            _Pragma("unroll")                                                     \
            for (int j = 0; j < 8; ++j)                                           \
                u[j] = __builtin_bit_cast(unsigned, base[j * STRIDE]) + 0x8000u;  \
            uint4 pk;                                                             \
            pk.x = (u[0] >> 16) | (u[1] & 0xFFFF0000u);                           \
            pk.y = (u[2] >> 16) | (u[3] & 0xFFFF0000u);                           \
            pk.z = (u[4] >> 16) | (u[5] & 0xFFFF0000u);                           \
            pk.w = (u[6] >> 16) | (u[7] & 0xFFFF0000u);                           \
            bfr[pt] = __builtin_bit_cast(short8, pk);                             \
        }                                                                         \
        _Pragma("unroll")                                                         \
        for (int ct = 0; ct < 4; ++ct) {                                          \
            const int sp = (2 * (c) - ct - 4 * wave) & 15;                        \
            const short8 af = *(const short8*)&afrags[sp * 512 + lane * 8];       \
            _Pragma("unroll")                                                     \
            for (int pt = 0; pt < 4; ++pt)                                        \
                acc[ct][pt] = __builtin_amdgcn_mfma_f32_16x16x32_bf16(            \
                    af, bfr[pt], acc[ct][pt], 0, 0, 0);                           \
        }                                                                         \
    }

    PHASE(0, 16)   // retires afrags + chunk0; chunks 1,2 stay in flight
    PHASE(1, 16)
    PHASE(2, 16)
    PHASE(3, 16)
    PHASE(4, 16)
    PHASE(5, 16)   // outstanding 6,7
    PHASE(6, 8)
    PHASE(7, 0)
#undef PHASE

    // ---- epilogue (verified layout rounds 0-5): D col=lane&15, row=quad*4+r ----
    // nt stores: out lines marked evict-first in L2/LLC (write-once data).
#pragma unroll
    for (int ct = 0; ct < 4; ++ct) {
#pragma unroll
        for (int r = 0; r < 4; ++r) {
            const int cc = wave * 64 + ct * 16 + quad * 4 + r;
            float* op = outn + (size_t)cc * HW + p0;
#pragma unroll
            for (int pt = 0; pt < 4; ++pt) {
                __builtin_nontemporal_store(acc[ct][pt][r], op + pt * 16 + m);
            }
        }
    }
}

extern "C" void kernel_launch(void* const* d_in, const int* in_sizes, int n_in,
                              void* d_out, int out_size, void* d_ws, size_t ws_size,
                              hipStream_t stream) {
    const float* act = (const float*)d_in[0];
    const float* filt = (const float*)d_in[1];
    float* out = (float*)d_out;
    unsigned short* tab = (unsigned short*)d_ws;   // 16384 bytes used

    build_tab_kernel<<<1, 256, 0, stream>>>(filt, tab);
    toeplitz_gemm_kernel<<<2048, 256, 0, stream>>>(act, tab, out);
}

// Round 7
// 253.605 us; speedup vs baseline: 1.0306x; 1.0026x over previous
//
#include <hip/hip_runtime.h>

#define C 256
#define HW 4096
#define STRIDE 66     // dwords per act row in LDS (64 px + 2 pad) -> verified 0-conflict read banks
#define CHROWS 32     // rows per K-chunk
#define NCHUNK 8
#define NBUF 4

typedef __attribute__((ext_vector_type(8))) short short8;
typedef __attribute__((ext_vector_type(4))) float float4v;

__device__ __forceinline__ unsigned short f2bf(float x) {
    unsigned u = __builtin_bit_cast(unsigned, x);
    u = (u + 0x7fffu + ((u >> 16) & 1u)) >> 16;
    return (unsigned short)u;
}

// async global->LDS DMA: 64 lanes x 4B, LDS dst = wave-uniform base + lane*4 (256 B/instr, full lines)
__device__ __forceinline__ void g2l_b32(const void* g, void* l) {
    __builtin_amdgcn_global_load_lds(
        (const __attribute__((address_space(1))) unsigned int*)g,
        (__attribute__((address_space(3))) unsigned int*)l, 4, 0, 0);
}

template <int N>
__device__ __forceinline__ void wait_vmcnt() {
    asm volatile("s_waitcnt vmcnt(%0)" :: "n"(N) : "memory");
    __builtin_amdgcn_sched_barrier(0);   // rule #18: pin -- nothing crosses the counted wait
}

// Kernel 1: one block. g = IDFT(1/(1 - DFT(kernel))). Output: two parity-shifted
// reversed-g dword tables (1056 B total) instead of the old 16-KB expanded tab.
//   grev[s] = bf16(g[(-s) & 255])           (s = 0..263, wrap absorbed by length)
//   tabA[i] = grev[2i]   | grev[2i+1]<<16   (i < 132)
//   tabB[i] = grev[2i+1] | grev[2i+2]<<16   (i < 131)
// An A-fragment for (sp, lane m,q) is shorts grev[s0..s0+7], s0=(16sp+8q-m)&255:
// 4 consecutive aligned dwords of tabA (s0 even) or tabB (s0 odd). Bit-exact
// reindexing of the previously verified tab (same f2bf values).
__global__ void build_tab_kernel(const float* __restrict__ filt, unsigned* __restrict__ tabw) {
    __shared__ float twc[256], tws[256];
    __shared__ float Gre[256], Gim[256];
    __shared__ float gsh[256];
    __shared__ unsigned short gb[256];
    const int t = threadIdx.x;
    const double PI = 3.14159265358979323846;
    double th = (double)t * (PI / 128.0);      // 2*pi*t/256
    twc[t] = (float)cos(th);
    tws[t] = (float)sin(th);
    __syncthreads();
    float re = 1.0f, im = 0.0f;
    for (int i = 0; i < 27; ++i) {
        int d = (243 + i) & 255;               // pad_roll layout offsets
        int idx = (t * d) & 255;
        float fv = filt[i];
        re -= fv * twc[idx];
        im += fv * tws[idx];
    }
    float den = re * re + im * im;
    Gre[t] = re / den;
    Gim[t] = -im / den;
    __syncthreads();
    float acc = 0.0f;
    for (int f = 0; f < 256; ++f) {
        int idx = (f * t) & 255;
        acc += Gre[f] * twc[idx] - Gim[f] * tws[idx];
    }
    gsh[t] = acc * (1.0f / 256.0f);
    gb[t] = f2bf(gsh[t]);                      // own element only; no sync needed before
    __syncthreads();
    // grev(s) = gb[(256 - s) & 255]
    if (t < 132)
        tabw[t] = (unsigned)gb[(256 - 2 * t) & 255]
                | ((unsigned)gb[(256 - (2 * t + 1)) & 255] << 16);
    if (t < 131)
        tabw[132 + t] = (unsigned)gb[(256 - (2 * t + 1)) & 255]
                      | ((unsigned)gb[(256 - (2 * t + 2)) & 255] << 16);
}

// Kernel 2: out[c,p] = sum_k W[c,k]*act[k,p].
// Round-4 structure (verified 87 us): 256 c x 64 px tile, full-line 256-B DMA reads,
// K pipelined in 8 chunks of 32 rows, 4 LDS buffers, counted s_waitcnt vmcnt(N) + raw
// s_barrier (prefetches never drained in the main loop), plain full-line stores.
// Round-7 delta: A-fragments read on the fly from the 1056-B parity tables instead of
// a 16-KB expanded table. LDS 50176 -> 34848 B => 4 blocks/CU (was 3 theoretical /
// ~2.4 observed). Latency-bound kernel: +50% resident waves => +~50% in-flight reads.
__global__ __launch_bounds__(256, 4)
void toeplitz_gemm_kernel(const float* __restrict__ act,
                          const unsigned* __restrict__ tabg,
                          float* __restrict__ out) {
    __shared__ float chunkbuf[NBUF][CHROWS * STRIDE];     // 4 x 8448 B = 33792 B
    __shared__ unsigned tabA[132];                        // 528 B
    __shared__ unsigned tabB[132];                        // 528 B  (total 34848 -> 4 blocks/CU)

    const int tid = threadIdx.x;
    const int wave = tid >> 6;
    const int lane = tid & 63;
    const int m = lane & 15;        // MFMA row (A) / col (B,D)
    const int quad = lane >> 4;     // k-subchunk selector
    const int blk = blockIdx.x;
    const int n = blk >> 6;                 // 64 px-tiles per image
    const int p0 = (blk & 63) << 6;
    const float* __restrict__ actn = act + (size_t)n * (C * HW);
    float* __restrict__ outn = out + (size_t)n * (C * HW);

    // ---- A-tables: 1056 B global -> LDS (one-time; compiler waits only these loads) ----
    if (tid < 132) tabA[tid] = tabg[tid];
    if (tid < 131) tabB[tid] = tabg[132 + tid];
    asm volatile("s_waitcnt lgkmcnt(0)" ::: "memory");   // own table writes drained pre-barrier

    // issue one 32-row chunk (8 full-line DMAs per wave)
    auto issue = [&](int ch) {
        const float* src = actn + (size_t)(ch * CHROWS + wave * 8) * HW + p0 + lane;
#pragma unroll
        for (int i = 0; i < 8; ++i)
            g2l_b32(src + (size_t)i * HW, &chunkbuf[ch & (NBUF - 1)][(wave * 8 + i) * STRIDE]);
    };

    issue(0); issue(1); issue(2);            // prologue: depth-3 in flight (24 outstanding)

    float4v acc[4][4];
#pragma unroll
    for (int ct = 0; ct < 4; ++ct)
#pragma unroll
        for (int pt = 0; pt < 4; ++pt)
            acc[ct][pt] = (float4v){0.f, 0.f, 0.f, 0.f};

    // Phase c: wait own chunk-c DMAs retired (<=16 outstanding keeps c+1,c+2 flying),
    // barrier makes chunk c (and, at phase 0, the A-tables) visible to all waves, then
    // issue c+3 (its buffer was last read in phase c-1; the phase-c barrier proves it
    // free), then compute.
#define PHASE(c, WN)                                                              \
    {                                                                             \
        wait_vmcnt<WN>();                                                         \
        __builtin_amdgcn_s_barrier();                                             \
        __builtin_amdgcn_sched_barrier(0);                                        \
        asm volatile("" ::: "memory");                                            \
        if ((c) + 3 < NCHUNK) issue((c) + 3);                                     \
        const float* cb = &chunkbuf[(c) & (NBUF - 1)][0];                         \
        short8 bfr[4];                                                            \
        _Pragma("unroll")                                                         \
        for (int pt = 0; pt < 4; ++pt) {                                          \
            const float* base = cb + (quad * 8) * STRIDE + pt * 16 + m;           \
            unsigned u[8];                                                        \
            _Pragma("unroll")                                                     \
            for (int j = 0; j < 8; ++j)                                           \
                u[j] = __builtin_bit_cast(unsigned, base[j * STRIDE]) + 0x8000u;  \
            uint4 pk;                                                             \
            pk.x = (u[0] >> 16) | (u[1] & 0xFFFF0000u);                           \
            pk.y = (u[2] >> 16) | (u[3] & 0xFFFF0000u);                           \
            pk.z = (u[4] >> 16) | (u[5] & 0xFFFF0000u);                           \
            pk.w = (u[6] >> 16) | (u[7] & 0xFFFF0000u);                           \
            bfr[pt] = __builtin_bit_cast(short8, pk);                             \
        }                                                                         \
        _Pragma("unroll")                                                         \
        for (int ct = 0; ct < 4; ++ct) {                                          \
            const int sp = (2 * (c) - ct - 4 * wave) & 15;                        \
            const int s0 = ((sp << 4) + (quad << 3) - m) & 255;                   \
            const unsigned* tp = ((s0 & 1) ? tabB : tabA) + (s0 >> 1);            \
            uint4 aw;                                                             \
            aw.x = tp[0]; aw.y = tp[1]; aw.z = tp[2]; aw.w = tp[3];               \
            const short8 af = __builtin_bit_cast(short8, aw);                     \
            _Pragma("unroll")                                                     \
            for (int pt = 0; pt < 4; ++pt)                                        \
                acc[ct][pt] = __builtin_amdgcn_mfma_f32_16x16x32_bf16(            \
                    af, bfr[pt], acc[ct][pt], 0, 0, 0);                           \
        }                                                                         \
    }

    PHASE(0, 16)   // retires chunk0; chunks 1,2 stay in flight
    PHASE(1, 16)
    PHASE(2, 16)
    PHASE(3, 16)
    PHASE(4, 16)
    PHASE(5, 16)   // outstanding 6,7
    PHASE(6, 8)
    PHASE(7, 0)
#undef PHASE

    // ---- epilogue (verified rounds 0-6): D layout col=lane&15, row=quad*4+r ----
#pragma unroll
    for (int ct = 0; ct < 4; ++ct) {
#pragma unroll
        for (int r = 0; r < 4; ++r) {
            const int cc = wave * 64 + ct * 16 + quad * 4 + r;
            float* op = outn + (size_t)cc * HW + p0;
#pragma unroll
            for (int pt = 0; pt < 4; ++pt) {
                op[pt * 16 + m] = acc[ct][pt][r];
            }
        }
    }
}

extern "C" void kernel_launch(void* const* d_in, const int* in_sizes, int n_in,
                              void* d_out, int out_size, void* d_ws, size_t ws_size,
                              hipStream_t stream) {
    const float* act = (const float*)d_in[0];
    const float* filt = (const float*)d_in[1];
    float* out = (float*)d_out;
    unsigned* tabw = (unsigned*)d_ws;   // 1052 bytes used

    build_tab_kernel<<<1, 256, 0, stream>>>(filt, tabw);
    toeplitz_gemm_kernel<<<2048, 256, 0, stream>>>(act, tabw, out);
}

// Round 8
// 252.046 us; speedup vs baseline: 1.0369x; 1.0062x over previous
//
#include <hip/hip_runtime.h>

#define C 256
#define HW 4096
#define CHROWS 32     // rows per K-chunk
#define NCHUNK 8
#define NBUF 4

typedef __attribute__((ext_vector_type(8))) short short8;
typedef __attribute__((ext_vector_type(4))) float float4v;

__device__ __forceinline__ unsigned short f2bf(float x) {
    unsigned u = __builtin_bit_cast(unsigned, x);
    u = (u + 0x7fffu + ((u >> 16) & 1u)) >> 16;
    return (unsigned short)u;
}

// async global->LDS DMA: 64 lanes x 16B, LDS dst = wave-uniform base + lane*16 (1 KB/request)
__device__ __forceinline__ void g2l_b128(const void* g, void* l) {
    __builtin_amdgcn_global_load_lds(
        (const __attribute__((address_space(1))) unsigned int*)g,
        (__attribute__((address_space(3))) unsigned int*)l, 16, 0, 0);
}

template <int N>
__device__ __forceinline__ void wait_vmcnt() {
    asm volatile("s_waitcnt vmcnt(%0)" :: "n"(N) : "memory");
    __builtin_amdgcn_sched_barrier(0);   // rule #18: pin -- nothing crosses the counted wait
}

// Kernel 1: one block. g = IDFT(1/(1 - DFT(kernel))). Output: two parity-shifted
// reversed-g dword tables (1056 B total).
//   grev[s] = bf16(g[(-s) & 255])
//   tabA[i] = grev[2i]   | grev[2i+1]<<16   (i < 132)
//   tabB[i] = grev[2i+1] | grev[2i+2]<<16   (i < 131)
// A-fragment (sp, lane m,q) = shorts grev[s0..s0+7], s0=(16sp+8q-m)&255: 4 consecutive
// aligned dwords of tabA (s0 even) or tabB (s0 odd). Verified bit-exact in round 7.
__global__ void build_tab_kernel(const float* __restrict__ filt, unsigned* __restrict__ tabw) {
    __shared__ float twc[256], tws[256];
    __shared__ float Gre[256], Gim[256];
    __shared__ float gsh[256];
    __shared__ unsigned short gb[256];
    const int t = threadIdx.x;
    const double PI = 3.14159265358979323846;
    double th = (double)t * (PI / 128.0);      // 2*pi*t/256
    twc[t] = (float)cos(th);
    tws[t] = (float)sin(th);
    __syncthreads();
    float re = 1.0f, im = 0.0f;
    for (int i = 0; i < 27; ++i) {
        int d = (243 + i) & 255;               // pad_roll layout offsets
        int idx = (t * d) & 255;
        float fv = filt[i];
        re -= fv * twc[idx];
        im += fv * tws[idx];
    }
    float den = re * re + im * im;
    Gre[t] = re / den;
    Gim[t] = -im / den;
    __syncthreads();
    float acc = 0.0f;
    for (int f = 0; f < 256; ++f) {
        int idx = (f * t) & 255;
        acc += Gre[f] * twc[idx] - Gim[f] * tws[idx];
    }
    gsh[t] = acc * (1.0f / 256.0f);
    gb[t] = f2bf(gsh[t]);
    __syncthreads();
    if (t < 132)
        tabw[t] = (unsigned)gb[(256 - 2 * t) & 255]
                | ((unsigned)gb[(256 - (2 * t + 1)) & 255] << 16);
    if (t < 131)
        tabw[132 + t] = (unsigned)gb[(256 - (2 * t + 1)) & 255]
                      | ((unsigned)gb[(256 - (2 * t + 2)) & 255] << 16);
}

// Kernel 2: out[c,p] = sum_k W[c,k]*act[k,p].
// R4 schedule (verified): 256 c x 64 px tile, 8 chunks of 32 rows, 4 LDS buffers,
// counted s_waitcnt vmcnt(N) + raw s_barrier, depth-3 prefetch.
// Round-8 delta: staging via global_load_lds WIDTH 16 (1 KB/request, 4x fewer requests,
// 4x bytes-in-flight under the per-CU DMA queue cap that R4/R7 counters exposed:
// delivered BW pinned at 9.1 GB/s/CU = ~32 x 256 B / 900 ns, occupancy-invariant).
// Linear [32][64] LDS layout (DMA requires it); bank spread restored by the involution
//   store: global seg s ^= ((row>>3)&3)<<2   (pre-swizzled source address)
//   read:  px col    ^= quad<<4              (wave-uniform, folds into (pt^quad)<<4)
// -> B-read aliasing 4-way -> 2-way (free, m136). Numerics byte-identical.
__global__ __launch_bounds__(256, 4)
void toeplitz_gemm_kernel(const float* __restrict__ act,
                          const unsigned* __restrict__ tabg,
                          float* __restrict__ out) {
    __shared__ __align__(16) float chunkbuf[NBUF][CHROWS * 64]; // 4 x 8192 B = 32768 B
    __shared__ unsigned tabA[132];                              // 528 B
    __shared__ unsigned tabB[132];                              // 528 B (tot 33824 -> 4 blk/CU)

    const int tid = threadIdx.x;
    const int wave = tid >> 6;
    const int lane = tid & 63;
    const int m = lane & 15;        // MFMA row (A) / col (B,D)
    const int quad = lane >> 4;     // k-subchunk selector
    const int blk = blockIdx.x;
    const int n = blk >> 6;                 // 64 px-tiles per image
    const int p0 = (blk & 63) << 6;
    const float* __restrict__ actn = act + (size_t)n * (C * HW);
    float* __restrict__ outn = out + (size_t)n * (C * HW);

    // ---- A-tables: 1056 B global -> LDS (register loads, compiler-drained pre-DMA) ----
    if (tid < 132) tabA[tid] = tabg[tid];
    if (tid < 131) tabB[tid] = tabg[132 + tid];
    asm volatile("s_waitcnt lgkmcnt(0)" ::: "memory");   // own table writes drained pre-barrier

    // issue one 32-row chunk: 2 x b128 DMA per wave (each = 4 rows x 256 B = 1 KB).
    // lane l covers row rbase+(l>>4), 16-B segment (l&15); source segment pre-swizzled.
    auto issue = [&](int ch) {
#pragma unroll
        for (int i = 0; i < 2; ++i) {
            const int rbase = wave * 8 + i * 4;            // rows rbase..rbase+3 of chunk
            const int r = rbase + (lane >> 4);
            const int s = (lane & 15) ^ (((r >> 3) & 3) << 2);   // swizzled 16-B segment
            const float* src = actn + (size_t)(ch * CHROWS + r) * HW + p0 + (s << 2);
            g2l_b128(src, &chunkbuf[ch & (NBUF - 1)][rbase * 64]);
        }
    };

    issue(0); issue(1); issue(2);            // prologue: depth-3 in flight (6 requests/wave)

    float4v acc[4][4];
#pragma unroll
    for (int ct = 0; ct < 4; ++ct)
#pragma unroll
        for (int pt = 0; pt < 4; ++pt)
            acc[ct][pt] = (float4v){0.f, 0.f, 0.f, 0.f};

    // Phase c: wait own chunk-c DMAs retired (4 left keeps c+1,c+2 flying), barrier
    // publishes chunk c (and, at phase 0, the A-tables), issue c+3 (its buffer was last
    // read in phase c-1; the phase-c barrier proves it free), then compute.
#define PHASE(c, WN)                                                              \
    {                                                                             \
        wait_vmcnt<WN>();                                                         \
        __builtin_amdgcn_s_barrier();                                             \
        __builtin_amdgcn_sched_barrier(0);                                        \
        asm volatile("" ::: "memory");                                            \
        if ((c) + 3 < NCHUNK) issue((c) + 3);                                     \
        const float* cb = &chunkbuf[(c) & (NBUF - 1)][0];                         \
        short8 bfr[4];                                                            \
        _Pragma("unroll")                                                         \
        for (int pt = 0; pt < 4; ++pt) {                                          \
            const float* base = cb + quad * 512 + ((pt ^ quad) << 4) + m;         \
            unsigned u[8];                                                        \
            _Pragma("unroll")                                                     \
            for (int j = 0; j < 8; ++j)                                           \
                u[j] = __builtin_bit_cast(unsigned, base[j * 64]) + 0x8000u;      \
            uint4 pk;                                                             \
            pk.x = (u[0] >> 16) | (u[1] & 0xFFFF0000u);                           \
            pk.y = (u[2] >> 16) | (u[3] & 0xFFFF0000u);                           \
            pk.z = (u[4] >> 16) | (u[5] & 0xFFFF0000u);                           \
            pk.w = (u[6] >> 16) | (u[7] & 0xFFFF0000u);                           \
            bfr[pt] = __builtin_bit_cast(short8, pk);                             \
        }                                                                         \
        _Pragma("unroll")                                                         \
        for (int ct = 0; ct < 4; ++ct) {                                          \
            const int sp = (2 * (c) - ct - 4 * wave) & 15;                        \
            const int s0 = ((sp << 4) + (quad << 3) - m) & 255;                   \
            const unsigned* tp = ((s0 & 1) ? tabB : tabA) + (s0 >> 1);            \
            uint4 aw;                                                             \
            aw.x = tp[0]; aw.y = tp[1]; aw.z = tp[2]; aw.w = tp[3];               \
            const short8 af = __builtin_bit_cast(short8, aw);                     \
            _Pragma("unroll")                                                     \
            for (int pt = 0; pt < 4; ++pt)                                        \
                acc[ct][pt] = __builtin_amdgcn_mfma_f32_16x16x32_bf16(            \
                    af, bfr[pt], acc[ct][pt], 0, 0, 0);                           \
        }                                                                         \
    }

    // vmcnt ledger (2 DMA/chunk/wave): prologue 6 out; steady wait 4 (retire chunk c),
    // issue +2 -> 6; tail 4 -> 2 -> 0.
    PHASE(0, 4)
    PHASE(1, 4)
    PHASE(2, 4)
    PHASE(3, 4)
    PHASE(4, 4)
    PHASE(5, 4)
    PHASE(6, 2)
    PHASE(7, 0)
#undef PHASE

    // ---- epilogue (verified rounds 0-7): D layout col=lane&15, row=quad*4+r ----
#pragma unroll
    for (int ct = 0; ct < 4; ++ct) {
#pragma unroll
        for (int r = 0; r < 4; ++r) {
            const int cc = wave * 64 + ct * 16 + quad * 4 + r;
            float* op = outn + (size_t)cc * HW + p0;
#pragma unroll
            for (int pt = 0; pt < 4; ++pt) {
                op[pt * 16 + m] = acc[ct][pt][r];
            }
        }
    }
}

extern "C" void kernel_launch(void* const* d_in, const int* in_sizes, int n_in,
                              void* d_out, int out_size, void* d_ws, size_t ws_size,
                              hipStream_t stream) {
    const float* act = (const float*)d_in[0];
    const float* filt = (const float*)d_in[1];
    float* out = (float*)d_out;
    unsigned* tabw = (unsigned*)d_ws;   // 1052 bytes used

    build_tab_kernel<<<1, 256, 0, stream>>>(filt, tabw);
    toeplitz_gemm_kernel<<<2048, 256, 0, stream>>>(act, tabw, out);
}